// Round 2
// baseline (1353.756 us; speedup 1.0000x reference)
//
#include <hip/hip_runtime.h>
#include <hip/hip_fp16.h>
#include <stdint.h>

#define Bn 8
#define Dd 512
#define Nn 2048

typedef _Float16 f16;
typedef __attribute__((ext_vector_type(8))) _Float16 f16x8;
typedef __attribute__((ext_vector_type(4))) _Float16 f16x4;
typedef __attribute__((ext_vector_type(4))) float f32x4;

// ---- workspace layout (f16 elements) ----
#define OFF_W    ((size_t)0)                       // 3 * 262144 (W as single f16)
#define OFF_XTH  ((size_t)786432)                  // x^T hi, [B][N][D]
#define OFF_XTL  ((size_t)(786432 + 1*8388608))    // x^T lo
#define OFF_Q    ((size_t)(786432 + 2*8388608))    // Q single f16 [B][N][D]
#define OFF_KH   ((size_t)(786432 + 3*8388608))    // K hi [B][N][D]
#define OFF_KL   ((size_t)(786432 + 4*8388608))    // K lo
#define OFF_VT   ((size_t)(786432 + 5*8388608))    // V^T single f16 [B][D][N]
// total 51,118,080 elems = 102.2 MB

static __device__ __forceinline__ f32x4 MFMA16(f16x8 a, f16x8 b, f32x4 c) {
  return __builtin_amdgcn_mfma_f32_16x16x32_f16(a, b, c, 0, 0, 0);
}

// ---------------------------------------------------------------------------
// k0a: W -> single f16 plane
__global__ void wcvt_kernel(const float* __restrict__ Wq,
                            const float* __restrict__ Wk,
                            const float* __restrict__ Wv,
                            f16* __restrict__ ws) {
  int idx = blockIdx.x * 256 + threadIdx.x;  // < 786432
  int p = idx >> 18;
  int e = idx & 262143;
  const float* W = (p == 0) ? Wq : ((p == 1) ? Wk : Wv);
  ws[OFF_W + idx] = (f16)W[e];
}

// ---------------------------------------------------------------------------
// k0b: transpose x [B][D][N] -> xt [B][N][D], split f16 hi/lo
__global__ void xtsplit_kernel(const float* __restrict__ x,
                               f16* __restrict__ ws) {
  __shared__ float t[32][33];
  int b = blockIdx.z, d0 = blockIdx.y * 32, n0 = blockIdx.x * 32;
  int tid = threadIdx.x;
  int r = tid >> 5, c = tid & 31;
  const float* xb = x + (size_t)b * Dd * Nn;
#pragma unroll
  for (int rr = 0; rr < 4; ++rr) {
    int dl = rr * 8 + r;
    t[dl][c] = xb[(size_t)(d0 + dl) * Nn + n0 + c];
  }
  __syncthreads();
  f16* xh = ws + OFF_XTH + (size_t)b * Nn * Dd;
  f16* xl = ws + OFF_XTL + (size_t)b * Nn * Dd;
#pragma unroll
  for (int rr = 0; rr < 4; ++rr) {
    int nl = rr * 8 + r;
    float v = t[c][nl];
    f16 h = (f16)v;
    int idx = (n0 + nl) * Dd + d0 + c;
    xh[idx] = h;
    xl[idx] = (f16)(v - (float)h);
  }
}

// ---------------------------------------------------------------------------
// k1: projection GEMM, 2-pass f16-split: y = xh*W + xl*W + b.
// grid (N/64, B, 3); 4 waves x 128 j-cols.
__global__ __launch_bounds__(256, 2) void proj_kernel(
    f16* __restrict__ ws,
    const float* __restrict__ bq, const float* __restrict__ bk,
    const float* __restrict__ bv) {
  int z = blockIdx.z, b = blockIdx.y, n0 = blockIdx.x * 64;
  const f16* Wp = ws + OFF_W + (size_t)z * 262144;
  const f16* xh = ws + OFF_XTH + (size_t)b * Nn * Dd;
  const f16* xl = ws + OFF_XTL + (size_t)b * Nn * Dd;
  int tid = threadIdx.x;
  int w = tid >> 6, l = tid & 63;
  int l16 = l & 15, lq = l >> 4;
  int j0 = w * 128;

  f32x4 acc[32];
#pragma unroll
  for (int i = 0; i < 32; ++i) acc[i] = (f32x4){0.f, 0.f, 0.f, 0.f};

  for (int ks = 0; ks < 16; ++ks) {
    f16x8 ah[4], al[4], bw[8];
#pragma unroll
    for (int rt = 0; rt < 4; ++rt) {
      int off = (n0 + rt * 16 + l16) * Dd + ks * 32 + lq * 8;
      ah[rt] = *(const f16x8*)(xh + off);
      al[rt] = *(const f16x8*)(xl + off);
    }
#pragma unroll
    for (int ct = 0; ct < 8; ++ct) {
      int woff = (j0 + ct * 16 + l16) * Dd + ks * 32 + lq * 8;
      bw[ct] = *(const f16x8*)(Wp + woff);
    }
#pragma unroll
    for (int ct = 0; ct < 8; ++ct)
#pragma unroll
      for (int rt = 0; rt < 4; ++rt)
        acc[rt * 8 + ct] = MFMA16(ah[rt], bw[ct], acc[rt * 8 + ct]);
#pragma unroll
    for (int ct = 0; ct < 8; ++ct)
#pragma unroll
      for (int rt = 0; rt < 4; ++rt)
        acc[rt * 8 + ct] = MFMA16(al[rt], bw[ct], acc[rt * 8 + ct]);
  }

  const float* bias = (z == 0) ? bq : ((z == 1) ? bk : bv);
  if (z == 0) {
    f16* Qp = ws + OFF_Q + (size_t)b * Nn * Dd;
#pragma unroll
    for (int ct = 0; ct < 8; ++ct) {
      int j = j0 + ct * 16 + l16;
      float bj = bias[j];
#pragma unroll
      for (int rt = 0; rt < 4; ++rt) {
        f32x4 a = acc[rt * 8 + ct];
#pragma unroll
        for (int r = 0; r < 4; ++r)
          Qp[(n0 + rt * 16 + lq * 4 + r) * Dd + j] = (f16)(a[r] + bj);
      }
    }
  } else if (z == 1) {
    f16* Oh = ws + OFF_KH + (size_t)b * Nn * Dd;
    f16* Ol = ws + OFF_KL + (size_t)b * Nn * Dd;
#pragma unroll
    for (int ct = 0; ct < 8; ++ct) {
      int j = j0 + ct * 16 + l16;
      float bj = bias[j];
#pragma unroll
      for (int rt = 0; rt < 4; ++rt) {
        f32x4 a = acc[rt * 8 + ct];
#pragma unroll
        for (int r = 0; r < 4; ++r) {
          float v = a[r] + bj;
          f16 h = (f16)v;
          int n = n0 + rt * 16 + lq * 4 + r;
          Oh[n * Dd + j] = h;
          Ol[n * Dd + j] = (f16)(v - (float)h);
        }
      }
    }
  } else {
    f16* Vt = ws + OFF_VT + (size_t)b * Dd * Nn;
#pragma unroll
    for (int ct = 0; ct < 8; ++ct) {
      int j = j0 + ct * 16 + l16;
      float bj = bias[j];
#pragma unroll
      for (int rt = 0; rt < 4; ++rt) {
        f32x4 a = acc[rt * 8 + ct];
        f16x4 hv;
#pragma unroll
        for (int r = 0; r < 4; ++r) hv[r] = (f16)(a[r] + bj);
        int nb = n0 + rt * 16 + lq * 4;
        *(f16x4*)(Vt + (size_t)j * Nn + nb) = hv;
      }
    }
  }
}

// ---------------------------------------------------------------------------
// k2: fused flash attention, 2-wave blocks (32 q rows), grid (N/32, B)=512.
// LDS (f16 elems): K hi [64][64] @0, K lo @4096, V [128][64] @8192,
// P per-wave [16][88] @16384. Total 19200 elems = 38400 B -> 4 blocks/CU.
__global__ __launch_bounds__(128, 2) void attn_kernel(
    const f16* __restrict__ ws, float* __restrict__ out) {
  __shared__ f16 lds[19200];
  int b = blockIdx.y, n0 = blockIdx.x * 32;
  int tid = threadIdx.x;
  int w = tid >> 6, l = tid & 63;
  int l16 = l & 15, lq = l >> 4;

  const f16* Q  = ws + OFF_Q  + (size_t)b * Nn * Dd;
  const f16* Kh = ws + OFF_KH + (size_t)b * Nn * Dd;
  const f16* Kl = ws + OFF_KL + (size_t)b * Nn * Dd;
  const f16* Vt = ws + OFF_VT + (size_t)b * Dd * Nn;

  // Q fragments: 16 q rows x full D, single f16 (A-layout: row = l16)
  f16x8 q[16];
  {
    int qrow = n0 + w * 16 + l16;
#pragma unroll
    for (int ks = 0; ks < 16; ++ks)
      q[ks] = *(const f16x8*)(Q + (size_t)qrow * Dd + ks * 32 + lq * 8);
  }

  f32x4 o[32];
#pragma unroll
  for (int i = 0; i < 32; ++i) o[i] = (f32x4){0.f, 0.f, 0.f, 0.f};
  float m[4], lsum[4];
#pragma unroll
  for (int r = 0; r < 4; ++r) { m[r] = -1e30f; lsum[r] = 0.f; }

  for (int kt = 0; kt < 32; ++kt) {
    int k0 = kt * 64;
    f32x4 s[4];
#pragma unroll
    for (int ct = 0; ct < 4; ++ct) s[ct] = (f32x4){0.f, 0.f, 0.f, 0.f};

    // ---- S = Q K^T over 8 d-chunks of 64 (K hi/lo in LDS, 2-pass)
    for (int dc = 0; dc < 8; ++dc) {
      __syncthreads();
      // stage K chunk: 2 planes x 64 rows x 8 slots(16B) = 1024 slots
#pragma unroll
      for (int j = 0; j < 8; ++j) {
        int slot = j * 128 + tid;
        int p = slot >> 9;
        int s9 = slot & 511;
        int row = s9 >> 3, c = s9 & 7;
        const f16* src = (p ? Kl : Kh) + (size_t)(k0 + row) * Dd + dc * 64 + c * 8;
        f16x8 tv = *(const f16x8*)src;
        *(f16x8*)&lds[p * 4096 + row * 64 + ((c * 8) ^ ((row & 7) << 3))] = tv;
      }
      __syncthreads();
#pragma unroll
      for (int ds = 0; ds < 2; ++ds) {
        int ksq = dc * 2 + ds;
        f16x8 kb[4];
#pragma unroll
        for (int ct = 0; ct < 4; ++ct) {
          int row = ct * 16 + l16;
          kb[ct] = *(const f16x8*)&lds[row * 64 +
                                       ((ds * 32 + lq * 8) ^ ((row & 7) << 3))];
        }
#pragma unroll
        for (int ct = 0; ct < 4; ++ct) s[ct] = MFMA16(q[ksq], kb[ct], s[ct]);
#pragma unroll
        for (int ct = 0; ct < 4; ++ct) {
          int row = ct * 16 + l16;
          kb[ct] = *(const f16x8*)&lds[4096 + row * 64 +
                                       ((ds * 32 + lq * 8) ^ ((row & 7) << 3))];
        }
#pragma unroll
        for (int ct = 0; ct < 4; ++ct) s[ct] = MFMA16(q[ksq], kb[ct], s[ct]);
      }
    }

    // ---- online softmax (rows q = lq*4+r live across l16 lane groups)
    float scl[4];
#pragma unroll
    for (int r = 0; r < 4; ++r) {
      float tm = fmaxf(fmaxf(s[0][r], s[1][r]), fmaxf(s[2][r], s[3][r]));
      tm = fmaxf(tm, __shfl_xor(tm, 1, 16));
      tm = fmaxf(tm, __shfl_xor(tm, 2, 16));
      tm = fmaxf(tm, __shfl_xor(tm, 4, 16));
      tm = fmaxf(tm, __shfl_xor(tm, 8, 16));
      float mn = fmaxf(m[r], tm);
      scl[r] = __expf(m[r] - mn);
      float ps = 0.f;
#pragma unroll
      for (int ct = 0; ct < 4; ++ct) {
        float p = __expf(s[ct][r] - mn);
        s[ct][r] = p;
        ps += p;
      }
      ps += __shfl_xor(ps, 1, 16);
      ps += __shfl_xor(ps, 2, 16);
      ps += __shfl_xor(ps, 4, 16);
      ps += __shfl_xor(ps, 8, 16);
      lsum[r] = lsum[r] * scl[r] + ps;
      m[r] = mn;
    }
#pragma unroll
    for (int i = 0; i < 32; ++i) {
      f32x4 t = o[i];
      t[0] *= scl[0]; t[1] *= scl[1]; t[2] *= scl[2]; t[3] *= scl[3];
      o[i] = t;
    }
    // P -> per-wave LDS buffer (stride 88 elems = 176 B, 16B-aligned rows)
#pragma unroll
    for (int ct = 0; ct < 4; ++ct)
#pragma unroll
      for (int r = 0; r < 4; ++r)
        lds[16384 + w * 1408 + (lq * 4 + r) * 88 + ct * 16 + l16] =
            (f16)s[ct][r];

    // ---- PV over 4 d-chunks of 128 (V in LDS)
    f16x8 pa0, pa1;
#pragma unroll
    for (int vc = 0; vc < 4; ++vc) {
      __syncthreads();
      // stage V chunk: 128 rows x 8 slots = 1024 slots
#pragma unroll
      for (int j = 0; j < 8; ++j) {
        int slot = j * 128 + tid;
        int row = slot >> 3, c = slot & 7;
        const f16* src = Vt + (size_t)(vc * 128 + row) * Nn + k0 + c * 8;
        f16x8 tv = *(const f16x8*)src;
        *(f16x8*)&lds[8192 + row * 64 + ((c * 8) ^ ((row & 7) << 3))] = tv;
      }
      __syncthreads();
      if (vc == 0) {
        pa0 = *(const f16x8*)&lds[16384 + w * 1408 + l16 * 88 + lq * 8];
        pa1 = *(const f16x8*)&lds[16384 + w * 1408 + l16 * 88 + 32 + lq * 8];
      }
#pragma unroll
      for (int kks = 0; kks < 2; ++kks) {
        f16x8 pa = kks ? pa1 : pa0;
#pragma unroll
        for (int ct2 = 0; ct2 < 8; ++ct2) {
          int row = ct2 * 16 + l16;
          f16x8 vb = *(const f16x8*)&lds[8192 + row * 64 +
                                         ((kks * 32 + lq * 8) ^ ((row & 7) << 3))];
          o[vc * 8 + ct2] = MFMA16(pa, vb, o[vc * 8 + ct2]);
        }
      }
    }
  }

  // ---- epilogue: O /= lsum, store out[b][d][n] (f32)
  float inv[4];
#pragma unroll
  for (int r = 0; r < 4; ++r) inv[r] = 1.0f / lsum[r];
  float* ob = out + (size_t)b * Dd * Nn;
  int nb = n0 + w * 16 + lq * 4;
#pragma unroll
  for (int i = 0; i < 32; ++i) {
    int d = (i >> 3) * 128 + (i & 7) * 16 + l16;
    f32x4 t = o[i];
    t[0] *= inv[0]; t[1] *= inv[1]; t[2] *= inv[2]; t[3] *= inv[3];
    *(f32x4*)(ob + (size_t)d * Nn + nb) = t;
  }
}

// ---------------------------------------------------------------------------
extern "C" void kernel_launch(void* const* d_in, const int* in_sizes, int n_in,
                              void* d_out, int out_size, void* d_ws,
                              size_t ws_size, hipStream_t stream) {
  const float* x  = (const float*)d_in[0];
  const float* Wq = (const float*)d_in[1];
  const float* bq = (const float*)d_in[2];
  const float* Wk = (const float*)d_in[3];
  const float* bk = (const float*)d_in[4];
  const float* Wv = (const float*)d_in[5];
  const float* bv = (const float*)d_in[6];
  f16* ws = (f16*)d_ws;
  float* out = (float*)d_out;

  hipLaunchKernelGGL(wcvt_kernel, dim3(3072), dim3(256), 0, stream,
                     Wq, Wk, Wv, ws);
  hipLaunchKernelGGL(xtsplit_kernel, dim3(Nn / 32, Dd / 32, Bn), dim3(256), 0,
                     stream, x, ws);
  hipLaunchKernelGGL(proj_kernel, dim3(Nn / 64, Bn, 3), dim3(256), 0, stream,
                     ws, bq, bk, bv);
  hipLaunchKernelGGL(attn_kernel, dim3(Nn / 32, Bn), dim3(128), 0, stream,
                     ws, out);
}

// Round 3
// 1010.436 us; speedup vs baseline: 1.3398x; 1.3398x over previous
//
#include <hip/hip_runtime.h>
#include <hip/hip_fp16.h>
#include <stdint.h>

#define Bn 8
#define Dd 512
#define Nn 2048

typedef _Float16 f16;
typedef __attribute__((ext_vector_type(8))) _Float16 f16x8;
typedef __attribute__((ext_vector_type(4))) _Float16 f16x4;
typedef __attribute__((ext_vector_type(4))) float f32x4;

// ---- workspace layout (f16 elements) ----
#define OFF_W    ((size_t)0)                       // 3 * 262144 (W as single f16)
#define OFF_XTH  ((size_t)786432)                  // x^T hi, [B][N][D]
#define OFF_XTL  ((size_t)(786432 + 1*8388608))    // x^T lo
#define OFF_Q    ((size_t)(786432 + 2*8388608))    // Q single f16 [B][N][D]
#define OFF_KH   ((size_t)(786432 + 3*8388608))    // K hi [B][N][D]
#define OFF_KL   ((size_t)(786432 + 4*8388608))    // K lo
#define OFF_VT   ((size_t)(786432 + 5*8388608))    // V^T single f16 [B][D][N]
#define OFF_END  ((size_t)(786432 + 6*8388608))    // 51118080; splitK partials after

static __device__ __forceinline__ f32x4 MFMA16(f16x8 a, f16x8 b, f32x4 c) {
  return __builtin_amdgcn_mfma_f32_16x16x32_f16(a, b, c, 0, 0, 0);
}

// async global->LDS, 16B per lane; lds dest must be wave-uniform base (+lane*16)
static __device__ __forceinline__ void gl16(const f16* g, f16* l) {
  __builtin_amdgcn_global_load_lds(
      (const __attribute__((address_space(1))) void*)(const void*)g,
      (__attribute__((address_space(3))) void*)(void*)l, 16, 0, 0);
}

// ---------------------------------------------------------------------------
// k0a: W -> single f16 plane
__global__ void wcvt_kernel(const float* __restrict__ Wq,
                            const float* __restrict__ Wk,
                            const float* __restrict__ Wv,
                            f16* __restrict__ ws) {
  int idx = blockIdx.x * 256 + threadIdx.x;  // < 786432
  int p = idx >> 18;
  int e = idx & 262143;
  const float* W = (p == 0) ? Wq : ((p == 1) ? Wk : Wv);
  ws[OFF_W + idx] = (f16)W[e];
}

// ---------------------------------------------------------------------------
// k0b: transpose x [B][D][N] -> xt [B][N][D], split f16 hi/lo
__global__ void xtsplit_kernel(const float* __restrict__ x,
                               f16* __restrict__ ws) {
  __shared__ float t[32][33];
  int b = blockIdx.z, d0 = blockIdx.y * 32, n0 = blockIdx.x * 32;
  int tid = threadIdx.x;
  int r = tid >> 5, c = tid & 31;
  const float* xb = x + (size_t)b * Dd * Nn;
#pragma unroll
  for (int rr = 0; rr < 4; ++rr) {
    int dl = rr * 8 + r;
    t[dl][c] = xb[(size_t)(d0 + dl) * Nn + n0 + c];
  }
  __syncthreads();
  f16* xh = ws + OFF_XTH + (size_t)b * Nn * Dd;
  f16* xl = ws + OFF_XTL + (size_t)b * Nn * Dd;
#pragma unroll
  for (int rr = 0; rr < 4; ++rr) {
    int nl = rr * 8 + r;
    float v = t[c][nl];
    f16 h = (f16)v;
    int idx = (n0 + nl) * Dd + d0 + c;
    xh[idx] = h;
    xl[idx] = (f16)(v - (float)h);
  }
}

// ---------------------------------------------------------------------------
// k1: projection GEMM, 2-pass f16-split: y = xh*W + xl*W + b.
__global__ __launch_bounds__(256, 2) void proj_kernel(
    f16* __restrict__ ws,
    const float* __restrict__ bq, const float* __restrict__ bk,
    const float* __restrict__ bv) {
  int z = blockIdx.z, b = blockIdx.y, n0 = blockIdx.x * 64;
  const f16* Wp = ws + OFF_W + (size_t)z * 262144;
  const f16* xh = ws + OFF_XTH + (size_t)b * Nn * Dd;
  const f16* xl = ws + OFF_XTL + (size_t)b * Nn * Dd;
  int tid = threadIdx.x;
  int w = tid >> 6, l = tid & 63;
  int l16 = l & 15, lq = l >> 4;
  int j0 = w * 128;

  f32x4 acc[32];
#pragma unroll
  for (int i = 0; i < 32; ++i) acc[i] = (f32x4){0.f, 0.f, 0.f, 0.f};

  for (int ks = 0; ks < 16; ++ks) {
    f16x8 ah[4], al[4], bw[8];
#pragma unroll
    for (int rt = 0; rt < 4; ++rt) {
      int off = (n0 + rt * 16 + l16) * Dd + ks * 32 + lq * 8;
      ah[rt] = *(const f16x8*)(xh + off);
      al[rt] = *(const f16x8*)(xl + off);
    }
#pragma unroll
    for (int ct = 0; ct < 8; ++ct) {
      int woff = (j0 + ct * 16 + l16) * Dd + ks * 32 + lq * 8;
      bw[ct] = *(const f16x8*)(Wp + woff);
    }
#pragma unroll
    for (int ct = 0; ct < 8; ++ct)
#pragma unroll
      for (int rt = 0; rt < 4; ++rt)
        acc[rt * 8 + ct] = MFMA16(ah[rt], bw[ct], acc[rt * 8 + ct]);
#pragma unroll
    for (int ct = 0; ct < 8; ++ct)
#pragma unroll
      for (int rt = 0; rt < 4; ++rt)
        acc[rt * 8 + ct] = MFMA16(al[rt], bw[ct], acc[rt * 8 + ct]);
  }

  const float* bias = (z == 0) ? bq : ((z == 1) ? bk : bv);
  if (z == 0) {
    f16* Qp = ws + OFF_Q + (size_t)b * Nn * Dd;
#pragma unroll
    for (int ct = 0; ct < 8; ++ct) {
      int j = j0 + ct * 16 + l16;
      float bj = bias[j];
#pragma unroll
      for (int rt = 0; rt < 4; ++rt) {
        f32x4 a = acc[rt * 8 + ct];
#pragma unroll
        for (int r = 0; r < 4; ++r)
          Qp[(n0 + rt * 16 + lq * 4 + r) * Dd + j] = (f16)(a[r] + bj);
      }
    }
  } else if (z == 1) {
    f16* Oh = ws + OFF_KH + (size_t)b * Nn * Dd;
    f16* Ol = ws + OFF_KL + (size_t)b * Nn * Dd;
#pragma unroll
    for (int ct = 0; ct < 8; ++ct) {
      int j = j0 + ct * 16 + l16;
      float bj = bias[j];
#pragma unroll
      for (int rt = 0; rt < 4; ++rt) {
        f32x4 a = acc[rt * 8 + ct];
#pragma unroll
        for (int r = 0; r < 4; ++r) {
          float v = a[r] + bj;
          f16 h = (f16)v;
          int n = n0 + rt * 16 + lq * 4 + r;
          Oh[n * Dd + j] = h;
          Ol[n * Dd + j] = (f16)(v - (float)h);
        }
      }
    }
  } else {
    f16* Vt = ws + OFF_VT + (size_t)b * Dd * Nn;
#pragma unroll
    for (int ct = 0; ct < 8; ++ct) {
      int j = j0 + ct * 16 + l16;
      float bj = bias[j];
#pragma unroll
      for (int rt = 0; rt < 4; ++rt) {
        f32x4 a = acc[rt * 8 + ct];
        f16x4 hv;
#pragma unroll
        for (int r = 0; r < 4; ++r) hv[r] = (f16)(a[r] + bj);
        int nb = n0 + rt * 16 + lq * 4;
        *(f16x4*)(Vt + (size_t)j * Nn + nb) = hv;
      }
    }
  }
}

// ---------------------------------------------------------------------------
// k2: split-K flash attention. grid (N/64, B, S); 4 waves x 16 q-rows.
// LDS: K hi [64][256] @0 (16384), K lo @16384 (16384), P @32768 (4x16x72).
// K staged via global_load_lds (pre-swizzled source); V direct from global;
// P per-wave-private (no barriers). 4 barriers per 64-key tile.
#define PB 32768

__global__ __launch_bounds__(256, 2) void attn_kernel(
    const f16* __restrict__ ws, f16* __restrict__ opart,
    float* __restrict__ mbuf, float* __restrict__ lbuf, int nkt) {
  __shared__ f16 lds[37376];
  const int b = blockIdx.y, n0 = blockIdx.x * 64, sp = blockIdx.z;
  const int tid = threadIdx.x;
  const int w = tid >> 6, l = tid & 63;
  const int l16 = l & 15, lq = l >> 4;

  const f16* Q  = ws + OFF_Q  + (size_t)b * Nn * Dd;
  const f16* Kh = ws + OFF_KH + (size_t)b * Nn * Dd;
  const f16* Kl = ws + OFF_KL + (size_t)b * Nn * Dd;
  const f16* Vt = ws + OFF_VT + (size_t)b * Dd * Nn;
  const int qrow = n0 + w * 16 + l16;

  f32x4 o[32];
#pragma unroll
  for (int i = 0; i < 32; ++i) o[i] = (f32x4){0.f, 0.f, 0.f, 0.f};
  float m[4], lsum[4];
#pragma unroll
  for (int r = 0; r < 4; ++r) { m[r] = -1e30f; lsum[r] = 0.f; }

  for (int kt = 0; kt < nkt; ++kt) {
    const int k0 = (sp * nkt + kt) * 64;
    f32x4 s4[4];
#pragma unroll
    for (int ct = 0; ct < 4; ++ct) s4[ct] = (f32x4){0.f, 0.f, 0.f, 0.f};

    // ---- S = Q K^T over 2 d-chunks of 256 (K hi/lo staged, 2-pass)
#pragma unroll
    for (int dc = 0; dc < 2; ++dc) {
      __syncthreads();
      // stage: 2 planes x 64 rows x 32 slots(16B) = 4096 slots, 16/lane
#pragma unroll
      for (int j = 0; j < 16; ++j) {
        int slot0 = (w * 16 + j) * 64;               // wave-uniform
        int slot = slot0 + l;
        int p = slot >> 11;
        int r9 = slot & 2047;
        int row = r9 >> 5, cs = r9 & 31;
        const f16* src = (p ? Kl : Kh) + (size_t)(k0 + row) * Dd + dc * 256 +
                         ((cs ^ (row & 7)) << 3);
        gl16(src, (f16*)&lds[(slot0 >> 11) * 16384 + (slot0 & 2047) * 8]);
      }
      __syncthreads();
      f16x8 qf[8];
#pragma unroll
      for (int ks = 0; ks < 8; ++ks)
        qf[ks] = *(const f16x8*)(Q + (size_t)qrow * Dd + dc * 256 + ks * 32 +
                                 lq * 8);
#pragma unroll
      for (int ks = 0; ks < 8; ++ks) {
        const int cs = ks * 4 + lq;
        f16x8 kb[4];
#pragma unroll
        for (int ct = 0; ct < 4; ++ct) {
          const int row = ct * 16 + l16;
          kb[ct] = *(const f16x8*)&lds[row * 256 + ((cs ^ (row & 7)) << 3)];
        }
#pragma unroll
        for (int ct = 0; ct < 4; ++ct) s4[ct] = MFMA16(qf[ks], kb[ct], s4[ct]);
#pragma unroll
        for (int ct = 0; ct < 4; ++ct) {
          const int row = ct * 16 + l16;
          kb[ct] =
              *(const f16x8*)&lds[16384 + row * 256 + ((cs ^ (row & 7)) << 3)];
        }
#pragma unroll
        for (int ct = 0; ct < 4; ++ct) s4[ct] = MFMA16(qf[ks], kb[ct], s4[ct]);
      }
    }

    // ---- online softmax (rows live across 16-lane groups)
    float scl[4];
#pragma unroll
    for (int r = 0; r < 4; ++r) {
      float tm = fmaxf(fmaxf(s4[0][r], s4[1][r]), fmaxf(s4[2][r], s4[3][r]));
      tm = fmaxf(tm, __shfl_xor(tm, 1, 16));
      tm = fmaxf(tm, __shfl_xor(tm, 2, 16));
      tm = fmaxf(tm, __shfl_xor(tm, 4, 16));
      tm = fmaxf(tm, __shfl_xor(tm, 8, 16));
      float mn = fmaxf(m[r], tm);
      scl[r] = __expf(m[r] - mn);
      float ps = 0.f;
#pragma unroll
      for (int ct = 0; ct < 4; ++ct) {
        float p = __expf(s4[ct][r] - mn);
        s4[ct][r] = p;
        ps += p;
      }
      ps += __shfl_xor(ps, 1, 16);
      ps += __shfl_xor(ps, 2, 16);
      ps += __shfl_xor(ps, 4, 16);
      ps += __shfl_xor(ps, 8, 16);
      lsum[r] = lsum[r] * scl[r] + ps;
      m[r] = mn;
    }
#pragma unroll
    for (int i = 0; i < 32; ++i) {
      f32x4 t = o[i];
      t[0] *= scl[0]; t[1] *= scl[1]; t[2] *= scl[2]; t[3] *= scl[3];
      o[i] = t;
    }
    // P -> per-wave-private LDS (no barrier needed; same-wave lgkmcnt only)
#pragma unroll
    for (int ct = 0; ct < 4; ++ct)
#pragma unroll
      for (int r = 0; r < 4; ++r)
        lds[PB + w * 1152 + (lq * 4 + r) * 72 + ct * 16 + l16] =
            (f16)s4[ct][r];
    asm volatile("s_waitcnt lgkmcnt(0)" ::: "memory");

    // ---- PV: O += P V, V direct from global (L2/L3-resident)
#pragma unroll
    for (int kks = 0; kks < 2; ++kks) {
      f16x8 pa =
          *(const f16x8*)&lds[PB + w * 1152 + l16 * 72 + kks * 32 + lq * 8];
#pragma unroll
      for (int i = 0; i < 32; ++i) {
        const int d = i * 16 + l16;
        f16x8 vb =
            *(const f16x8*)(Vt + (size_t)d * Nn + k0 + kks * 32 + lq * 8);
        o[i] = MFMA16(pa, vb, o[i]);
      }
    }
  }

  // ---- epilogue: write unnormalized partial O (f16) + m, l
  f16* opb = opart + ((size_t)sp * Bn + b) * Dd * Nn;
  const int nbase = n0 + w * 16 + lq * 4;
#pragma unroll
  for (int i = 0; i < 32; ++i) {
    const int d = i * 16 + l16;
    f16x4 hv;
#pragma unroll
    for (int r = 0; r < 4; ++r) hv[r] = (f16)o[i][r];
    *(f16x4*)(opb + (size_t)d * Nn + nbase) = hv;
  }
  if (l16 == 0) {
    size_t msl = ((size_t)sp * Bn + b) * Nn;
#pragma unroll
    for (int r = 0; r < 4; ++r) {
      mbuf[msl + nbase + r] = m[r];
      lbuf[msl + nbase + r] = lsum[r];
    }
  }
}

// ---------------------------------------------------------------------------
// k3: merge splits -> out[b][d][n] f32
template <int S>
__global__ __launch_bounds__(256) void merge_kernel(
    const f16* __restrict__ opart, const float* __restrict__ mbuf,
    const float* __restrict__ lbuf, float* __restrict__ out) {
  int idx = blockIdx.x * 256 + threadIdx.x;   // < B*D*N/8 = 1048576
  int nb = (idx & 255) * 8;
  int d = (idx >> 8) & 511;
  int b = idx >> 17;

  float ms[4][8], ls[4][8];
#pragma unroll
  for (int s = 0; s < S; ++s) {
    const float* mp = mbuf + ((size_t)s * Bn + b) * Nn + nb;
    const float* lp = lbuf + ((size_t)s * Bn + b) * Nn + nb;
    f32x4 a0 = *(const f32x4*)mp, a1 = *(const f32x4*)(mp + 4);
    f32x4 c0 = *(const f32x4*)lp, c1 = *(const f32x4*)(lp + 4);
#pragma unroll
    for (int j = 0; j < 4; ++j) {
      ms[s][j] = a0[j]; ms[s][4 + j] = a1[j];
      ls[s][j] = c0[j]; ls[s][4 + j] = c1[j];
    }
  }
  float M[8], den[8], acc[8];
#pragma unroll
  for (int j = 0; j < 8; ++j) M[j] = ms[0][j];
#pragma unroll
  for (int s = 1; s < S; ++s)
#pragma unroll
    for (int j = 0; j < 8; ++j) M[j] = fmaxf(M[j], ms[s][j]);
#pragma unroll
  for (int j = 0; j < 8; ++j) { den[j] = 0.f; acc[j] = 0.f; }
#pragma unroll
  for (int s = 0; s < S; ++s) {
    const f16* op = opart + (((size_t)s * Bn + b) * Dd + d) * Nn + nb;
    f16x8 ov = *(const f16x8*)op;
#pragma unroll
    for (int j = 0; j < 8; ++j) {
      float wgt = __expf(ms[s][j] - M[j]);
      den[j] += ls[s][j] * wgt;
      acc[j] += (float)ov[j] * wgt;
    }
  }
  float* po = out + ((size_t)b * Dd + d) * Nn + nb;
  f32x4 r0, r1;
#pragma unroll
  for (int j = 0; j < 4; ++j) {
    r0[j] = acc[j] / den[j];
    r1[j] = acc[4 + j] / den[4 + j];
  }
  *(f32x4*)po = r0;
  *(f32x4*)(po + 4) = r1;
}

// ---------------------------------------------------------------------------
extern "C" void kernel_launch(void* const* d_in, const int* in_sizes, int n_in,
                              void* d_out, int out_size, void* d_ws,
                              size_t ws_size, hipStream_t stream) {
  const float* x  = (const float*)d_in[0];
  const float* Wq = (const float*)d_in[1];
  const float* bq = (const float*)d_in[2];
  const float* Wk = (const float*)d_in[3];
  const float* bk = (const float*)d_in[4];
  const float* Wv = (const float*)d_in[5];
  const float* bv = (const float*)d_in[6];
  f16* ws = (f16*)d_ws;
  float* out = (float*)d_out;

  // choose split factor from available workspace
  int S = 1;
  {
    size_t need4 = (OFF_END + 4ull * 8388608) * 2 + 4ull * 131072;
    size_t need2 = (OFF_END + 2ull * 8388608) * 2 + 2ull * 131072;
    if (ws_size >= need4) S = 4;
    else if (ws_size >= need2) S = 2;
  }
  f16* opart = ws + OFF_END;
  float* mbuf = (float*)(opart + (size_t)S * 8388608);
  float* lbuf = mbuf + (size_t)S * Bn * Nn;

  hipLaunchKernelGGL(wcvt_kernel, dim3(3072), dim3(256), 0, stream,
                     Wq, Wk, Wv, ws);
  hipLaunchKernelGGL(xtsplit_kernel, dim3(Nn / 32, Dd / 32, Bn), dim3(256), 0,
                     stream, x, ws);
  hipLaunchKernelGGL(proj_kernel, dim3(Nn / 64, Bn, 3), dim3(256), 0, stream,
                     ws, bq, bk, bv);
  hipLaunchKernelGGL(attn_kernel, dim3(Nn / 64, Bn, S), dim3(256), 0, stream,
                     ws, opart, mbuf, lbuf, 32 / S);
  switch (S) {
    case 4:
      hipLaunchKernelGGL((merge_kernel<4>), dim3(4096), dim3(256), 0, stream,
                         opart, mbuf, lbuf, out);
      break;
    case 2:
      hipLaunchKernelGGL((merge_kernel<2>), dim3(4096), dim3(256), 0, stream,
                         opart, mbuf, lbuf, out);
      break;
    default:
      hipLaunchKernelGGL((merge_kernel<1>), dim3(4096), dim3(256), 0, stream,
                         opart, mbuf, lbuf, out);
      break;
  }
}

// Round 4
// 719.377 us; speedup vs baseline: 1.8818x; 1.4046x over previous
//
#include <hip/hip_runtime.h>
#include <hip/hip_fp16.h>
#include <stdint.h>

#define Bn 8
#define Dd 512
#define Nn 2048

typedef _Float16 f16;
typedef __attribute__((ext_vector_type(8))) _Float16 f16x8;
typedef __attribute__((ext_vector_type(4))) _Float16 f16x4;
typedef __attribute__((ext_vector_type(4))) float f32x4;

// ---- workspace layout (f16 elements) ----
#define OFF_W    ((size_t)0)                       // 3 * 262144 (W as single f16)
#define OFF_XTH  ((size_t)786432)                  // x^T hi, [B][N][D]
#define OFF_XTL  ((size_t)(786432 + 1*8388608))    // x^T lo
#define OFF_Q    ((size_t)(786432 + 2*8388608))    // Q single f16 [B][N][D]
#define OFF_KH   ((size_t)(786432 + 3*8388608))    // K hi [B][N][D]
#define OFF_KL   ((size_t)(786432 + 4*8388608))    // K lo
#define OFF_VT   ((size_t)(786432 + 5*8388608))    // V^T single f16 [B][D][N]
#define OFF_END  ((size_t)(786432 + 6*8388608))    // splitK partials after

static __device__ __forceinline__ f32x4 MFMA16(f16x8 a, f16x8 b, f32x4 c) {
  return __builtin_amdgcn_mfma_f32_16x16x32_f16(a, b, c, 0, 0, 0);
}

// async global->LDS, 16B/lane; lds dest = wave-uniform base + lane*16
static __device__ __forceinline__ void gl16(const f16* g, f16* l) {
  __builtin_amdgcn_global_load_lds(
      (const __attribute__((address_space(1))) void*)(const void*)g,
      (__attribute__((address_space(3))) void*)(void*)l, 16, 0, 0);
}

// ---------------------------------------------------------------------------
__global__ void wcvt_kernel(const float* __restrict__ Wq,
                            const float* __restrict__ Wk,
                            const float* __restrict__ Wv,
                            f16* __restrict__ ws) {
  int idx = blockIdx.x * 256 + threadIdx.x;  // < 786432
  int p = idx >> 18;
  int e = idx & 262143;
  const float* W = (p == 0) ? Wq : ((p == 1) ? Wk : Wv);
  ws[OFF_W + idx] = (f16)W[e];
}

// ---------------------------------------------------------------------------
__global__ void xtsplit_kernel(const float* __restrict__ x,
                               f16* __restrict__ ws) {
  __shared__ float t[32][33];
  int b = blockIdx.z, d0 = blockIdx.y * 32, n0 = blockIdx.x * 32;
  int tid = threadIdx.x;
  int r = tid >> 5, c = tid & 31;
  const float* xb = x + (size_t)b * Dd * Nn;
#pragma unroll
  for (int rr = 0; rr < 4; ++rr) {
    int dl = rr * 8 + r;
    t[dl][c] = xb[(size_t)(d0 + dl) * Nn + n0 + c];
  }
  __syncthreads();
  f16* xh = ws + OFF_XTH + (size_t)b * Nn * Dd;
  f16* xl = ws + OFF_XTL + (size_t)b * Nn * Dd;
#pragma unroll
  for (int rr = 0; rr < 4; ++rr) {
    int nl = rr * 8 + r;
    float v = t[c][nl];
    f16 h = (f16)v;
    int idx = (n0 + nl) * Dd + d0 + c;
    xh[idx] = h;
    xl[idx] = (f16)(v - (float)h);
  }
}

// ---------------------------------------------------------------------------
// k1: projection GEMM, 2-pass f16-split: y = xh*W + xl*W + b.
__global__ __launch_bounds__(256, 2) void proj_kernel(
    f16* __restrict__ ws,
    const float* __restrict__ bq, const float* __restrict__ bk,
    const float* __restrict__ bv) {
  int z = blockIdx.z, b = blockIdx.y, n0 = blockIdx.x * 64;
  const f16* Wp = ws + OFF_W + (size_t)z * 262144;
  const f16* xh = ws + OFF_XTH + (size_t)b * Nn * Dd;
  const f16* xl = ws + OFF_XTL + (size_t)b * Nn * Dd;
  int tid = threadIdx.x;
  int w = tid >> 6, l = tid & 63;
  int l16 = l & 15, lq = l >> 4;
  int j0 = w * 128;

  f32x4 acc[32];
#pragma unroll
  for (int i = 0; i < 32; ++i) acc[i] = (f32x4){0.f, 0.f, 0.f, 0.f};

  for (int ks = 0; ks < 16; ++ks) {
    f16x8 ah[4], al[4], bw[8];
#pragma unroll
    for (int rt = 0; rt < 4; ++rt) {
      int off = (n0 + rt * 16 + l16) * Dd + ks * 32 + lq * 8;
      ah[rt] = *(const f16x8*)(xh + off);
      al[rt] = *(const f16x8*)(xl + off);
    }
#pragma unroll
    for (int ct = 0; ct < 8; ++ct) {
      int woff = (j0 + ct * 16 + l16) * Dd + ks * 32 + lq * 8;
      bw[ct] = *(const f16x8*)(Wp + woff);
    }
#pragma unroll
    for (int ct = 0; ct < 8; ++ct)
#pragma unroll
      for (int rt = 0; rt < 4; ++rt)
        acc[rt * 8 + ct] = MFMA16(ah[rt], bw[ct], acc[rt * 8 + ct]);
#pragma unroll
    for (int ct = 0; ct < 8; ++ct)
#pragma unroll
      for (int rt = 0; rt < 4; ++rt)
        acc[rt * 8 + ct] = MFMA16(al[rt], bw[ct], acc[rt * 8 + ct]);
  }

  const float* bias = (z == 0) ? bq : ((z == 1) ? bk : bv);
  if (z == 0) {
    f16* Qp = ws + OFF_Q + (size_t)b * Nn * Dd;
#pragma unroll
    for (int ct = 0; ct < 8; ++ct) {
      int j = j0 + ct * 16 + l16;
      float bj = bias[j];
#pragma unroll
      for (int rt = 0; rt < 4; ++rt) {
        f32x4 a = acc[rt * 8 + ct];
#pragma unroll
        for (int r = 0; r < 4; ++r)
          Qp[(n0 + rt * 16 + lq * 4 + r) * Dd + j] = (f16)(a[r] + bj);
      }
    }
  } else if (z == 1) {
    f16* Oh = ws + OFF_KH + (size_t)b * Nn * Dd;
    f16* Ol = ws + OFF_KL + (size_t)b * Nn * Dd;
#pragma unroll
    for (int ct = 0; ct < 8; ++ct) {
      int j = j0 + ct * 16 + l16;
      float bj = bias[j];
#pragma unroll
      for (int rt = 0; rt < 4; ++rt) {
        f32x4 a = acc[rt * 8 + ct];
#pragma unroll
        for (int r = 0; r < 4; ++r) {
          float v = a[r] + bj;
          f16 h = (f16)v;
          int n = n0 + rt * 16 + lq * 4 + r;
          Oh[n * Dd + j] = h;
          Ol[n * Dd + j] = (f16)(v - (float)h);
        }
      }
    }
  } else {
    f16* Vt = ws + OFF_VT + (size_t)b * Dd * Nn;
#pragma unroll
    for (int ct = 0; ct < 8; ++ct) {
      int j = j0 + ct * 16 + l16;
      float bj = bias[j];
#pragma unroll
      for (int rt = 0; rt < 4; ++rt) {
        f32x4 a = acc[rt * 8 + ct];
        f16x4 hv;
#pragma unroll
        for (int r = 0; r < 4; ++r) hv[r] = (f16)(a[r] + bj);
        int nb = n0 + rt * 16 + lq * 4;
        *(f16x4*)(Vt + (size_t)j * Nn + nb) = hv;
      }
    }
  }
}

// ---------------------------------------------------------------------------
// k2: split-K flash attention, 8 waves x 16 q-rows = 128 q-rows/block.
// Grid: 128*S blocks (1D) with XCD swizzle so the 16 blocks sharing one
// (b,sp) K/V slice co-reside on one XCD -> slice is L2-resident.
// LDS (f16 elems): KH [64][256] @0, KL @16384, V [512][64] @32768,
// P 8x16x72 @65536. 74752 elems = 149504 B -> 1 block/CU, 8 waves/CU.
#define KH_O 0
#define KL_O 16384
#define V_O  32768
#define P_O  65536

__global__ __launch_bounds__(512, 2) void attn_kernel(
    const f16* __restrict__ ws, f16* __restrict__ opart,
    float* __restrict__ mbuf, float* __restrict__ lbuf, int nkt, int lgS) {
  __shared__ f16 lds[74752];
  const int S = 1 << lgS;
  const int cpx = gridDim.x >> 3;
  const int orig = blockIdx.x;
  const int lid = (orig & 7) * cpx + (orig >> 3);
  const int group = lid >> 4, tile = lid & 15;
  const int b = group >> lgS, sp = group & (S - 1);
  const int n0 = tile * 128;

  const int tid = threadIdx.x;
  const int w = tid >> 6, l = tid & 63;
  const int l16 = l & 15, lq = l >> 4;

  const f16* Q  = ws + OFF_Q  + (size_t)b * Nn * Dd;
  const f16* Kh = ws + OFF_KH + (size_t)b * Nn * Dd;
  const f16* Kl = ws + OFF_KL + (size_t)b * Nn * Dd;
  const f16* Vt = ws + OFF_VT + (size_t)b * Dd * Nn;
  const int qrow = n0 + w * 16 + l16;

  // Q held in regs: 16 x f16x8 (64 VGPRs)
  f16x8 q[16];
#pragma unroll
  for (int ks = 0; ks < 16; ++ks)
    q[ks] = *(const f16x8*)(Q + (size_t)qrow * Dd + ks * 32 + lq * 8);

  f32x4 o[32];
#pragma unroll
  for (int i = 0; i < 32; ++i) o[i] = (f32x4){0.f, 0.f, 0.f, 0.f};
  float m[4], lsum[4];
#pragma unroll
  for (int r = 0; r < 4; ++r) { m[r] = -1e30f; lsum[r] = 0.f; }

  for (int kt = 0; kt < nkt; ++kt) {
    const int k0 = (sp * nkt + kt) * 64;
    f32x4 s4[4];
#pragma unroll
    for (int ct = 0; ct < 4; ++ct) s4[ct] = (f32x4){0.f, 0.f, 0.f, 0.f};

#pragma unroll
    for (int dc = 0; dc < 2; ++dc) {
      __syncthreads();
      if (dc == 0) {
        // stage V [512][64]: 4096 slots, 8/thread (pre-swizzled source)
#pragma unroll
        for (int j = 0; j < 8; ++j) {
          int slot0 = j * 512 + w * 64;   // wave-uniform
          int slot = slot0 + l;
          int d = slot >> 3, c = slot & 7;
          const f16* src = Vt + (size_t)d * Nn + k0 + ((c ^ (d & 7)) << 3);
          gl16(src, (f16*)&lds[V_O + slot0 * 8]);
        }
      }
      // stage K chunk hi+lo: 2 planes x 64 rows x 32 slots = 4096, 8/thread
#pragma unroll
      for (int j = 0; j < 8; ++j) {
        int slot0 = j * 512 + w * 64;     // 64-slot chunk, single plane
        int plane = slot0 >> 11;
        int s11_0 = slot0 & 2047;
        int s11 = s11_0 + l;
        int row = s11 >> 5, cs = s11 & 31;
        const f16* src = (plane ? Kl : Kh) + (size_t)(k0 + row) * Dd +
                         dc * 256 + ((cs ^ (row & 7)) << 3);
        gl16(src, (f16*)&lds[plane * 16384 + s11_0 * 8]);
      }
      __syncthreads();
      // QK^T on this 256-d chunk, hi then lo plane
#pragma unroll
      for (int ks = 0; ks < 8; ++ks) {
        const int ksq = dc * 8 + ks;
        const int cs = ks * 4 + lq;
        f16x8 kb[4];
#pragma unroll
        for (int ct = 0; ct < 4; ++ct) {
          const int row = ct * 16 + l16;
          kb[ct] =
              *(const f16x8*)&lds[KH_O + row * 256 + ((cs ^ (row & 7)) << 3)];
        }
#pragma unroll
        for (int ct = 0; ct < 4; ++ct) s4[ct] = MFMA16(q[ksq], kb[ct], s4[ct]);
#pragma unroll
        for (int ct = 0; ct < 4; ++ct) {
          const int row = ct * 16 + l16;
          kb[ct] =
              *(const f16x8*)&lds[KL_O + row * 256 + ((cs ^ (row & 7)) << 3)];
        }
#pragma unroll
        for (int ct = 0; ct < 4; ++ct) s4[ct] = MFMA16(q[ksq], kb[ct], s4[ct]);
      }
    }

    // ---- online softmax (rows live across 16-lane groups)
    float scl[4];
#pragma unroll
    for (int r = 0; r < 4; ++r) {
      float tm = fmaxf(fmaxf(s4[0][r], s4[1][r]), fmaxf(s4[2][r], s4[3][r]));
      tm = fmaxf(tm, __shfl_xor(tm, 1, 16));
      tm = fmaxf(tm, __shfl_xor(tm, 2, 16));
      tm = fmaxf(tm, __shfl_xor(tm, 4, 16));
      tm = fmaxf(tm, __shfl_xor(tm, 8, 16));
      float mn = fmaxf(m[r], tm);
      scl[r] = __expf(m[r] - mn);
      float ps = 0.f;
#pragma unroll
      for (int ct = 0; ct < 4; ++ct) {
        float p = __expf(s4[ct][r] - mn);
        s4[ct][r] = p;
        ps += p;
      }
      ps += __shfl_xor(ps, 1, 16);
      ps += __shfl_xor(ps, 2, 16);
      ps += __shfl_xor(ps, 4, 16);
      ps += __shfl_xor(ps, 8, 16);
      lsum[r] = lsum[r] * scl[r] + ps;
      m[r] = mn;
    }
#pragma unroll
    for (int i = 0; i < 32; ++i) {
      f32x4 t = o[i];
      t[0] *= scl[0]; t[1] *= scl[1]; t[2] *= scl[2]; t[3] *= scl[3];
      o[i] = t;
    }
    // P -> per-wave-private LDS (no barrier; same-wave lgkmcnt only)
#pragma unroll
    for (int ct = 0; ct < 4; ++ct)
#pragma unroll
      for (int r = 0; r < 4; ++r)
        lds[P_O + w * 1152 + (lq * 4 + r) * 72 + ct * 16 + l16] =
            (f16)s4[ct][r];
    asm volatile("s_waitcnt lgkmcnt(0)" ::: "memory");

    // ---- PV from LDS V (protected by dc-loop barriers / next-iter barrier)
#pragma unroll
    for (int kks = 0; kks < 2; ++kks) {
      f16x8 pa =
          *(const f16x8*)&lds[P_O + w * 1152 + l16 * 72 + kks * 32 + lq * 8];
      const int c = kks * 4 + lq;
#pragma unroll
      for (int i = 0; i < 32; ++i) {
        const int d = i * 16 + l16;
        f16x8 vb = *(const f16x8*)&lds[V_O + d * 64 + ((c ^ (d & 7)) << 3)];
        o[i] = MFMA16(pa, vb, o[i]);
      }
    }
  }

  // ---- epilogue: unnormalized partial O (f16) + m, l
  f16* opb = opart + ((size_t)sp * Bn + b) * Dd * Nn;
  const int nbase = n0 + w * 16 + lq * 4;
#pragma unroll
  for (int i = 0; i < 32; ++i) {
    const int d = i * 16 + l16;
    f16x4 hv;
#pragma unroll
    for (int r = 0; r < 4; ++r) hv[r] = (f16)o[i][r];
    *(f16x4*)(opb + (size_t)d * Nn + nbase) = hv;
  }
  if (l16 == 0) {
    size_t msl = ((size_t)sp * Bn + b) * Nn;
#pragma unroll
    for (int r = 0; r < 4; ++r) {
      mbuf[msl + nbase + r] = m[r];
      lbuf[msl + nbase + r] = lsum[r];
    }
  }
}

// ---------------------------------------------------------------------------
template <int S>
__global__ __launch_bounds__(256) void merge_kernel(
    const f16* __restrict__ opart, const float* __restrict__ mbuf,
    const float* __restrict__ lbuf, float* __restrict__ out) {
  int idx = blockIdx.x * 256 + threadIdx.x;   // < B*D*N/8
  int nb = (idx & 255) * 8;
  int d = (idx >> 8) & 511;
  int b = idx >> 17;

  float ms[4][8], ls[4][8];
#pragma unroll
  for (int s = 0; s < S; ++s) {
    const float* mp = mbuf + ((size_t)s * Bn + b) * Nn + nb;
    const float* lp = lbuf + ((size_t)s * Bn + b) * Nn + nb;
    f32x4 a0 = *(const f32x4*)mp, a1 = *(const f32x4*)(mp + 4);
    f32x4 c0 = *(const f32x4*)lp, c1 = *(const f32x4*)(lp + 4);
#pragma unroll
    for (int j = 0; j < 4; ++j) {
      ms[s][j] = a0[j]; ms[s][4 + j] = a1[j];
      ls[s][j] = c0[j]; ls[s][4 + j] = c1[j];
    }
  }
  float M[8], den[8], acc[8];
#pragma unroll
  for (int j = 0; j < 8; ++j) M[j] = ms[0][j];
#pragma unroll
  for (int s = 1; s < S; ++s)
#pragma unroll
    for (int j = 0; j < 8; ++j) M[j] = fmaxf(M[j], ms[s][j]);
#pragma unroll
  for (int j = 0; j < 8; ++j) { den[j] = 0.f; acc[j] = 0.f; }
#pragma unroll
  for (int s = 0; s < S; ++s) {
    const f16* op = opart + (((size_t)s * Bn + b) * Dd + d) * Nn + nb;
    f16x8 ov = *(const f16x8*)op;
#pragma unroll
    for (int j = 0; j < 8; ++j) {
      float wgt = __expf(ms[s][j] - M[j]);
      den[j] += ls[s][j] * wgt;
      acc[j] += (float)ov[j] * wgt;
    }
  }
  float* po = out + ((size_t)b * Dd + d) * Nn + nb;
  f32x4 r0, r1;
#pragma unroll
  for (int j = 0; j < 4; ++j) {
    r0[j] = acc[j] / den[j];
    r1[j] = acc[4 + j] / den[4 + j];
  }
  *(f32x4*)po = r0;
  *(f32x4*)(po + 4) = r1;
}

// ---------------------------------------------------------------------------
extern "C" void kernel_launch(void* const* d_in, const int* in_sizes, int n_in,
                              void* d_out, int out_size, void* d_ws,
                              size_t ws_size, hipStream_t stream) {
  const float* x  = (const float*)d_in[0];
  const float* Wq = (const float*)d_in[1];
  const float* bq = (const float*)d_in[2];
  const float* Wk = (const float*)d_in[3];
  const float* bk = (const float*)d_in[4];
  const float* Wv = (const float*)d_in[5];
  const float* bv = (const float*)d_in[6];
  f16* ws = (f16*)d_ws;
  float* out = (float*)d_out;

  int S = 1, lgS = 0;
  {
    size_t need4 = (OFF_END + 4ull * 8388608) * 2 + 4ull * 131072;
    size_t need2 = (OFF_END + 2ull * 8388608) * 2 + 2ull * 131072;
    if (ws_size >= need4) { S = 4; lgS = 2; }
    else if (ws_size >= need2) { S = 2; lgS = 1; }
  }
  f16* opart = ws + OFF_END;
  float* mbuf = (float*)(opart + (size_t)S * 8388608);
  float* lbuf = mbuf + (size_t)S * Bn * Nn;

  hipLaunchKernelGGL(wcvt_kernel, dim3(3072), dim3(256), 0, stream,
                     Wq, Wk, Wv, ws);
  hipLaunchKernelGGL(xtsplit_kernel, dim3(Nn / 32, Dd / 32, Bn), dim3(256), 0,
                     stream, x, ws);
  hipLaunchKernelGGL(proj_kernel, dim3(Nn / 64, Bn, 3), dim3(256), 0, stream,
                     ws, bq, bk, bv);
  hipLaunchKernelGGL(attn_kernel, dim3(128 * S), dim3(512), 0, stream,
                     ws, opart, mbuf, lbuf, 32 / S, lgS);
  switch (S) {
    case 4:
      hipLaunchKernelGGL((merge_kernel<4>), dim3(4096), dim3(256), 0, stream,
                         opart, mbuf, lbuf, out);
      break;
    case 2:
      hipLaunchKernelGGL((merge_kernel<2>), dim3(4096), dim3(256), 0, stream,
                         opart, mbuf, lbuf, out);
      break;
    default:
      hipLaunchKernelGGL((merge_kernel<1>), dim3(4096), dim3(256), 0, stream,
                         opart, mbuf, lbuf, out);
      break;
  }
}